// Round 7
// baseline (428.051 us; speedup 1.0000x reference)
//
#include <hip/hip_runtime.h>
#include <cmath>

// ---------------------------------------------------------------------------
// GraphTransformerLayer on MI355X (gfx950).
// N=50000 nodes, C=128, H=8 heads, D=16, E=800000 edges (+N self loops).
//
// Pipeline (12 dispatches):
//   zero -> CSR build (count/scan x3/fill)      [edge_index arrives as INT32]
//   k_cast x->bf16 ; k_prep weights -> bf16 [Cout][K]
//   k_stream<0,3>: QKV B-in-regs streaming GEMM -> qkv bf16 [N][384]
//   k_attn: 1 wave/dest node, 8-edge batches    -> ob bf16
//   k_woln: streaming GEMM + bias+resid+LN1     -> x1b bf16 (resid = xb bf16)
//   k_ffn : fused FFN1+gelu+FFN2+resid+LN2      -> d_out fp32 (resid = x1b)
//
// r5/r6 lessons baked in: fused FFN saves the 102MB hb round-trip but must
// keep >=3 resident blocks/CU to hide its barriers -> 64-row tiles, 256 thr,
// 33KB LDS (4 blocks/CU), 782 blocks. K=128 GEMMs stay barrier-free
// (B-slice in 64 VGPRs/wave). All residuals read bf16 (x1f eliminated).
// ---------------------------------------------------------------------------

typedef short bf16x8 __attribute__((ext_vector_type(8)));
typedef float f32x4 __attribute__((ext_vector_type(4)));
typedef unsigned int uint_as1 __attribute__((address_space(1)));
typedef unsigned int uint_as3 __attribute__((address_space(3)));

__device__ inline unsigned short f2bf(float f) {
    unsigned int u = __float_as_uint(f);
    u += 0x7fffu + ((u >> 16) & 1u);   // round-to-nearest-even
    return (unsigned short)(u >> 16);
}
__device__ inline float bflo(unsigned int w) { return __uint_as_float(w << 16); }
__device__ inline float bfhi(unsigned int w) { return __uint_as_float(w & 0xffff0000u); }
__device__ inline float b2f(unsigned short u) { return __uint_as_float((unsigned int)u << 16); }

__device__ inline void gload16(const unsigned short* g, unsigned short* l) {
    __builtin_amdgcn_global_load_lds((const uint_as1*)g, (uint_as3*)l, 16, 0, 0);
}

// MFMA A/B fragment from a swizzled 64-row x 128-col LDS tile.
// slot(row, chunk) = kt*4096 + row*64 + (chunk ^ (row&7))*8  (kt = K-half).
__device__ inline bf16x8 ldfrag64(const unsigned short* t, int row, int ks, int quad) {
    int ch = (ks & 1) * 4 + quad;
    int pos = ch ^ (row & 7);
    return *(const bf16x8*)&t[(ks >> 1) * 4096 + row * 64 + pos * 8];
}

// ------------------------------- CSR build ---------------------------------

__global__ void k_zero(int* __restrict__ p, int n) {
    int i = blockIdx.x * 256 + threadIdx.x;
    if (i < n) p[i] = 0;
}

__global__ void k_count(const int* __restrict__ ei, int* __restrict__ counts,
                        int E, int N) {
    int e = blockIdx.x * 256 + threadIdx.x;
    if (e >= E + N) return;
    int col = (e < E) ? ei[E + e] : (e - E);
    atomicAdd(&counts[col], 1);
}

__global__ void k_scan1(const int* __restrict__ counts, int* __restrict__ incl,
                        int* __restrict__ bsums, int N) {
    __shared__ int s[256];
    int t = threadIdx.x, i = blockIdx.x * 256 + t;
    int v = (i < N) ? counts[i] : 0;
    s[t] = v; __syncthreads();
    for (int off = 1; off < 256; off <<= 1) {
        int add = (t >= off) ? s[t - off] : 0;
        __syncthreads();
        s[t] += add;
        __syncthreads();
    }
    if (i < N) incl[i] = s[t];
    if (t == 255) bsums[blockIdx.x] = s[255];
}

__global__ void k_scan2(const int* __restrict__ bsums, int* __restrict__ boffs, int NB) {
    __shared__ int s[256];
    int t = threadIdx.x;
    int v = (t < NB) ? bsums[t] : 0;
    s[t] = v; __syncthreads();
    for (int off = 1; off < 256; off <<= 1) {
        int add = (t >= off) ? s[t - off] : 0;
        __syncthreads();
        s[t] += add;
        __syncthreads();
    }
    if (t < NB) boffs[t] = s[t] - v;   // exclusive
}

__global__ void k_scan3(const int* __restrict__ incl, const int* __restrict__ counts,
                        const int* __restrict__ boffs, int* __restrict__ nstart,
                        int* __restrict__ cursor, int N) {
    int i = blockIdx.x * 256 + threadIdx.x;
    if (i >= N) return;
    int st = incl[i] - counts[i] + boffs[blockIdx.x];
    nstart[i] = st;
    cursor[i] = st;
}

__global__ void k_fill(const int* __restrict__ ei, int* __restrict__ cursor,
                       int* __restrict__ csr, int E, int N) {
    int e = blockIdx.x * 256 + threadIdx.x;
    if (e >= E + N) return;
    int row, col;
    if (e < E) { row = ei[e]; col = ei[E + e]; }
    else       { row = col = e - E; }
    int pos = atomicAdd(&cursor[col], 1);
    csr[pos] = row;
}

// ------------------------------ prep (casts) -------------------------------

__global__ void k_cast(const float* __restrict__ x, unsigned short* __restrict__ xb,
                       int total4) {
    int i = blockIdx.x * 256 + threadIdx.x;
    if (i >= total4) return;
    float4 v = ((const float4*)x)[i];
    ushort4 o;
    o.x = f2bf(v.x); o.y = f2bf(v.y); o.z = f2bf(v.z); o.w = f2bf(v.w);
    ((ushort4*)xb)[i] = o;
}

// transpose fp32 [K][Co] -> bf16 [Co][K].  Wq/Wk/Wv land contiguously.
__global__ void k_prep(const float* Wq, const float* Wk, const float* Wv, const float* Wo,
                       const float* Wf1, const float* Wf2,
                       unsigned short* Wqkvt, unsigned short* Wot,
                       unsigned short* Wf1t, unsigned short* Wf2t) {
    int z = blockIdx.y;
    const float* in; unsigned short* out; int K, Co;
    switch (z) {
        case 0: in = Wq;  out = Wqkvt;          K = 128; Co = 128; break;
        case 1: in = Wk;  out = Wqkvt + 16384;  K = 128; Co = 128; break;
        case 2: in = Wv;  out = Wqkvt + 32768;  K = 128; Co = 128; break;
        case 3: in = Wo;  out = Wot;            K = 128; Co = 128; break;
        case 4: in = Wf1; out = Wf1t;           K = 128; Co = 512; break;
        default: in = Wf2; out = Wf2t;          K = 512; Co = 128; break;
    }
    int idx = blockIdx.x * 256 + threadIdx.x;
    if (idx >= K * Co) return;
    int k = idx / Co, c = idx % Co;
    out[c * K + k] = f2bf(in[idx]);
}

// ------------------- streaming GEMM helpers (K=128) ------------------------
// Wave job: 32 rows (m0) x 64 cols (n0). B-slice preloaded into 16 regs.

__device__ inline void load_breg(const unsigned short* __restrict__ Bt, int n0,
                                 int l16, int quad, bf16x8 Breg[4][4]) {
#pragma unroll
    for (int tj = 0; tj < 4; ++tj) {
        const bf16x8* Br = (const bf16x8*)(Bt + (size_t)(n0 + tj * 16 + l16) * 128);
#pragma unroll
        for (int ks = 0; ks < 4; ++ks) Breg[ks][tj] = Br[ks * 4 + quad];
    }
}

__device__ inline void mfma_strip(const unsigned short* __restrict__ A, int m0, int M,
                                  int l16, int quad, const bf16x8 Breg[4][4],
                                  f32x4 acc[2][4]) {
    int ra0 = m0 + l16;      if (ra0 > M - 1) ra0 = M - 1;
    int ra1 = m0 + 16 + l16; if (ra1 > M - 1) ra1 = M - 1;
    const bf16x8* A0 = (const bf16x8*)(A + (size_t)ra0 * 128);
    const bf16x8* A1 = (const bf16x8*)(A + (size_t)ra1 * 128);
#pragma unroll
    for (int ks = 0; ks < 4; ++ks) {
        bf16x8 a0 = A0[ks * 4 + quad];
        bf16x8 a1 = A1[ks * 4 + quad];
#pragma unroll
        for (int tj = 0; tj < 4; ++tj) {
            acc[0][tj] = __builtin_amdgcn_mfma_f32_16x16x32_bf16(a0, Breg[ks][tj], acc[0][tj], 0, 0, 0);
            acc[1][tj] = __builtin_amdgcn_mfma_f32_16x16x32_bf16(a1, Breg[ks][tj], acc[1][tj], 0, 0, 0);
        }
    }
}

// ------------------------------- QKV GEMM ----------------------------------

template <int EPI, int NW>
__global__ __launch_bounds__(NW * 64) void k_stream(
    const unsigned short* __restrict__ A, const unsigned short* __restrict__ Bt,
    const float* __restrict__ bias, unsigned short* __restrict__ outb,
    int M, int Cout) {
    int tid = threadIdx.x;
    int wid = tid >> 6, lane = tid & 63;
    int quad = lane >> 4, l16 = lane & 15;
    int m0 = blockIdx.x * 32;
    int n0 = blockIdx.y * (NW * 64) + wid * 64;

    bf16x8 Breg[4][4];
    load_breg(Bt, n0, l16, quad, Breg);

    f32x4 acc[2][4];
#pragma unroll
    for (int i = 0; i < 2; ++i)
#pragma unroll
        for (int j = 0; j < 4; ++j) acc[i][j] = {0.f, 0.f, 0.f, 0.f};

    mfma_strip(A, m0, M, l16, quad, Breg, acc);

#pragma unroll
    for (int ti = 0; ti < 2; ++ti)
#pragma unroll
        for (int tj = 0; tj < 4; ++tj) {
            int col = n0 + tj * 16 + l16;
            float bi = (EPI == 1) ? bias[col] : 0.f;
#pragma unroll
            for (int r = 0; r < 4; ++r) {
                int row = m0 + ti * 16 + quad * 4 + r;
                if (row >= M) continue;
                float v = acc[ti][tj][r];
                if constexpr (EPI == 1) {
                    float gg = v + bi;
                    v = 0.5f * gg * (1.f + erff(gg * 0.70710678118f));
                }
                outb[(size_t)row * Cout + col] = f2bf(v);
            }
        }
}

// ------------------- Wo GEMM + bias + resid(bf16) + LN1 --------------------
// Block = 128 thr (2 waves), 32 rows; wave wid covers cols wid*64. K=128.

__global__ __launch_bounds__(128) void k_woln(
    const unsigned short* __restrict__ A, const unsigned short* __restrict__ Bt,
    const float* __restrict__ bias, const unsigned short* __restrict__ residb,
    const float* __restrict__ g, const float* __restrict__ b,
    unsigned short* __restrict__ outb, int M) {
    __shared__ float pS[2][32], pQ[2][32];
    int tid = threadIdx.x;
    int wid = tid >> 6, lane = tid & 63;
    int quad = lane >> 4, l16 = lane & 15;
    int m0 = blockIdx.x * 32;
    int n0 = wid * 64;

    bf16x8 Breg[4][4];
    load_breg(Bt, n0, l16, quad, Breg);
    f32x4 acc[2][4];
#pragma unroll
    for (int i = 0; i < 2; ++i)
#pragma unroll
        for (int j = 0; j < 4; ++j) acc[i][j] = {0.f, 0.f, 0.f, 0.f};
    mfma_strip(A, m0, M, l16, quad, Breg, acc);

#pragma unroll
    for (int tj = 0; tj < 4; ++tj) {
        int col = n0 + tj * 16 + l16;
        float bi = bias[col];
#pragma unroll
        for (int ti = 0; ti < 2; ++ti)
#pragma unroll
            for (int r = 0; r < 4; ++r) {
                int row = m0 + ti * 16 + quad * 4 + r;
                float rv = (row < M) ? b2f(residb[(size_t)row * 128 + col]) : 0.f;
                acc[ti][tj][r] += bi + rv;
            }
    }
#pragma unroll
    for (int ti = 0; ti < 2; ++ti)
#pragma unroll
        for (int r = 0; r < 4; ++r) {
            float s = acc[ti][0][r] + acc[ti][1][r] + acc[ti][2][r] + acc[ti][3][r];
            float q = acc[ti][0][r] * acc[ti][0][r] + acc[ti][1][r] * acc[ti][1][r]
                    + acc[ti][2][r] * acc[ti][2][r] + acc[ti][3][r] * acc[ti][3][r];
            s += __shfl_xor(s, 1); q += __shfl_xor(q, 1);
            s += __shfl_xor(s, 2); q += __shfl_xor(q, 2);
            s += __shfl_xor(s, 4); q += __shfl_xor(q, 4);
            s += __shfl_xor(s, 8); q += __shfl_xor(q, 8);
            if (l16 == 0) {
                int lr = ti * 16 + quad * 4 + r;
                pS[wid][lr] = s; pQ[wid][lr] = q;
            }
        }
    __syncthreads();
#pragma unroll
    for (int ti = 0; ti < 2; ++ti)
#pragma unroll
        for (int r = 0; r < 4; ++r) {
            int lr = ti * 16 + quad * 4 + r;
            int row = m0 + lr;
            if (row >= M) continue;
            float s = pS[0][lr] + pS[1][lr];
            float q = pQ[0][lr] + pQ[1][lr];
            float mean = s * 0.0078125f;
            float var = q * 0.0078125f - mean * mean;
            float rs = rsqrtf(var + 1e-5f);
#pragma unroll
            for (int tj = 0; tj < 4; ++tj) {
                int col = n0 + tj * 16 + l16;
                outb[(size_t)row * 128 + col] =
                    f2bf((acc[ti][tj][r] - mean) * rs * g[col] + b[col]);
            }
        }
}

// ---------------- fused FFN1 + gelu + FFN2 + resid + LN2 -------------------
// Block = 256 thr (4 waves 2x2), 64 rows. As = x1 tile (16KB, swizzled).
// Per hidden chunk c (128): GEMM1 (Wf1 streamed) -> gelu -> Hs (16KB,
// A-layout) -> GEMM2 (Wf2 streamed) accumulates. 33KB LDS -> 4 blocks/CU.

__global__ __launch_bounds__(256) void k_ffn(
    const unsigned short* __restrict__ x1b, const unsigned short* __restrict__ Wf1t,
    const float* __restrict__ bf1, const unsigned short* __restrict__ Wf2t,
    const float* __restrict__ bf2, const float* __restrict__ g2,
    const float* __restrict__ b2, float* __restrict__ outp, int M) {
    __shared__ unsigned short As[8192];
    __shared__ unsigned short Hs[8192];
    __shared__ float pS[2][64], pQ[2][64], mv[128];

    int tid = threadIdx.x;
    int wid = tid >> 6, lane = tid & 63;
    int quad = lane >> 4, l16 = lane & 15;
    int wr = wid >> 1, wc = wid & 1;
    int m0 = blockIdx.x * 64;

    int rsub = lane >> 3, gch = (lane & 7) ^ rsub;
#pragma unroll
    for (int kt = 0; kt < 2; ++kt)
#pragma unroll
        for (int j = 0; j < 2; ++j) {
            int ra = m0 + j * 32 + wid * 8 + rsub; if (ra > M - 1) ra = M - 1;
            gload16(x1b + (size_t)ra * 128 + kt * 64 + gch * 8,
                    As + kt * 4096 + j * 2048 + wid * 512 + lane * 8);
        }
    __syncthreads();

    f32x4 oacc[2][4];
#pragma unroll
    for (int i = 0; i < 2; ++i)
#pragma unroll
        for (int j = 0; j < 4; ++j) oacc[i][j] = {0.f, 0.f, 0.f, 0.f};

    const bf16x8* B2row[4];
#pragma unroll
    for (int tj = 0; tj < 4; ++tj)
        B2row[tj] = (const bf16x8*)(Wf2t + (size_t)(wc * 64 + tj * 16 + l16) * 512);

    for (int c = 0; c < 4; ++c) {
        // GEMM1: h chunk rows [wr*32,+32) x hcols [wc*64,+64) of chunk c
        f32x4 hacc[2][4];
#pragma unroll
        for (int i = 0; i < 2; ++i)
#pragma unroll
            for (int j = 0; j < 4; ++j) hacc[i][j] = {0.f, 0.f, 0.f, 0.f};
        const bf16x8* B1row[4];
#pragma unroll
        for (int tj = 0; tj < 4; ++tj)
            B1row[tj] = (const bf16x8*)(Wf1t +
                (size_t)(c * 128 + wc * 64 + tj * 16 + l16) * 128);
#pragma unroll
        for (int ks = 0; ks < 4; ++ks) {
            bf16x8 a0 = ldfrag64(As, wr * 32 + l16, ks, quad);
            bf16x8 a1 = ldfrag64(As, wr * 32 + 16 + l16, ks, quad);
#pragma unroll
            for (int tj = 0; tj < 4; ++tj) {
                bf16x8 bfr = B1row[tj][ks * 4 + quad];
                hacc[0][tj] = __builtin_amdgcn_mfma_f32_16x16x32_bf16(a0, bfr, hacc[0][tj], 0, 0, 0);
                hacc[1][tj] = __builtin_amdgcn_mfma_f32_16x16x32_bf16(a1, bfr, hacc[1][tj], 0, 0, 0);
            }
        }
        __syncthreads();   // prior GEMM2 readers done with Hs
        // gelu -> Hs (C-layout -> swizzled A-layout)
#pragma unroll
        for (int tj = 0; tj < 4; ++tj) {
            int k = wc * 64 + tj * 16 + l16;          // 0..127 within chunk
            float bv = bf1[c * 128 + k];
            int kt = k >> 6, kk = k & 63;
#pragma unroll
            for (int ti = 0; ti < 2; ++ti)
#pragma unroll
                for (int r = 0; r < 4; ++r) {
                    int row = wr * 32 + ti * 16 + quad * 4 + r;
                    float gg = hacc[ti][tj][r] + bv;
                    float y = 0.5f * gg * (1.f + erff(gg * 0.70710678118f));
                    Hs[kt * 4096 + row * 64 + (((kk >> 3) ^ (row & 7)) * 8) + (kk & 7)] = f2bf(y);
                }
        }
        __syncthreads();   // Hs complete
        // GEMM2: out += Hs @ Wf2[c*128 .. c*128+128)
#pragma unroll
        for (int ks = 0; ks < 4; ++ks) {
            bf16x8 a0 = ldfrag64(Hs, wr * 32 + l16, ks, quad);
            bf16x8 a1 = ldfrag64(Hs, wr * 32 + 16 + l16, ks, quad);
#pragma unroll
            for (int tj = 0; tj < 4; ++tj) {
                bf16x8 bfr = B2row[tj][c * 16 + ks * 4 + quad];
                oacc[0][tj] = __builtin_amdgcn_mfma_f32_16x16x32_bf16(a0, bfr, oacc[0][tj], 0, 0, 0);
                oacc[1][tj] = __builtin_amdgcn_mfma_f32_16x16x32_bf16(a1, bfr, oacc[1][tj], 0, 0, 0);
            }
        }
    }

    // epilogue: + bf2 + resid(x1b bf16) + LN2 -> fp32
    float gv[4], bv2[4], biv[4];
#pragma unroll
    for (int tj = 0; tj < 4; ++tj) {
        int col = wc * 64 + tj * 16 + l16;
        biv[tj] = bf2[col]; gv[tj] = g2[col]; bv2[tj] = b2[col];
    }
#pragma unroll
    for (int ti = 0; ti < 2; ++ti)
#pragma unroll
        for (int tj = 0; tj < 4; ++tj) {
            int col = wc * 64 + tj * 16 + l16;
#pragma unroll
            for (int r = 0; r < 4; ++r) {
                int row = m0 + wr * 32 + ti * 16 + quad * 4 + r;
                float rv = (row < M) ? b2f(x1b[(size_t)row * 128 + col]) : 0.f;
                oacc[ti][tj][r] += biv[tj] + rv;
            }
        }
#pragma unroll
    for (int ti = 0; ti < 2; ++ti)
#pragma unroll
        for (int r = 0; r < 4; ++r) {
            int lr = wr * 32 + ti * 16 + quad * 4 + r;   // 0..63
            float s = oacc[ti][0][r] + oacc[ti][1][r] + oacc[ti][2][r] + oacc[ti][3][r];
            float q = oacc[ti][0][r] * oacc[ti][0][r] + oacc[ti][1][r] * oacc[ti][1][r]
                    + oacc[ti][2][r] * oacc[ti][2][r] + oacc[ti][3][r] * oacc[ti][3][r];
            s += __shfl_xor(s, 1); q += __shfl_xor(q, 1);
            s += __shfl_xor(s, 2); q += __shfl_xor(q, 2);
            s += __shfl_xor(s, 4); q += __shfl_xor(q, 4);
            s += __shfl_xor(s, 8); q += __shfl_xor(q, 8);
            if (l16 == 0) { pS[wc][lr] = s; pQ[wc][lr] = q; }
        }
    __syncthreads();
    if (tid < 64) {
        float s = pS[0][tid] + pS[1][tid];
        float q = pQ[0][tid] + pQ[1][tid];
        float mean = s * 0.0078125f;
        float var = q * 0.0078125f - mean * mean;
        mv[tid] = mean;
        mv[64 + tid] = rsqrtf(var + 1e-5f);
    }
    __syncthreads();
#pragma unroll
    for (int ti = 0; ti < 2; ++ti)
#pragma unroll
        for (int r = 0; r < 4; ++r) {
            int lr = wr * 32 + ti * 16 + quad * 4 + r;
            int row = m0 + lr;
            if (row >= M) continue;
            float mean = mv[lr], rs = mv[64 + lr];
#pragma unroll
            for (int tj = 0; tj < 4; ++tj) {
                int col = wc * 64 + tj * 16 + l16;
                outp[(size_t)row * 128 + col] = (oacc[ti][tj][r] - mean) * rs * gv[tj] + bv2[tj];
            }
        }
}

// ------------------------------ attention ----------------------------------
// One wave per destination node j; qkv row = [q|k|v] (192 dwords). Lane l
// owns channels (2l,2l+1); lanes 8h..8h+7 hold head h -> 3 shfl_xor reduce.
// 8-edge batches: 16 gathers in flight, one batched online-softmax update.

__global__ __launch_bounds__(256) void k_attn(
    const unsigned int* __restrict__ qkv, const int* __restrict__ nstart,
    const int* __restrict__ counts, const int* __restrict__ csr,
    unsigned int* __restrict__ ob, int N) {
    int j = blockIdx.x * 4 + (threadIdx.x >> 6);
    if (j >= N) return;
    int l = threadIdx.x & 63;

    unsigned int kw = qkv[(size_t)j * 192 + 64 + l];
    float kx = bflo(kw), ky = bfhi(kw);

    int start = nstart[j], cnt = counts[j];
    float m = -3.0e38f, lsum = 0.f, a0 = 0.f, a1 = 0.f;
    int i = 0;
    for (; i + 8 <= cnt; i += 8) {
        int ri[8];
#pragma unroll
        for (int u = 0; u < 8; ++u) ri[u] = csr[start + i + u];
        unsigned int qw[8], vw[8];
#pragma unroll
        for (int u = 0; u < 8; ++u) qw[u] = qkv[(size_t)ri[u] * 192 + l];
#pragma unroll
        for (int u = 0; u < 8; ++u) vw[u] = qkv[(size_t)ri[u] * 192 + 128 + l];

        float p[8];
#pragma unroll
        for (int u = 0; u < 8; ++u) p[u] = fmaf(bflo(qw[u]), kx, bfhi(qw[u]) * ky);
#pragma unroll
        for (int u = 0; u < 8; ++u) p[u] += __shfl_xor(p[u], 1);
#pragma unroll
        for (int u = 0; u < 8; ++u) p[u] += __shfl_xor(p[u], 2);
#pragma unroll
        for (int u = 0; u < 8; ++u) p[u] += __shfl_xor(p[u], 4);

        float mx = m;
#pragma unroll
        for (int u = 0; u < 8; ++u) { p[u] *= 0.25f; mx = fmaxf(mx, p[u]); }
        float scale = __expf(m - mx);
        float e[8], es = 0.f, va = 0.f, vb = 0.f;
#pragma unroll
        for (int u = 0; u < 8; ++u) {
            e[u] = __expf(p[u] - mx);
            es += e[u];
            va = fmaf(e[u], bflo(vw[u]), va);
            vb = fmaf(e[u], bfhi(vw[u]), vb);
        }
        lsum = lsum * scale + es;
        a0 = a0 * scale + va;
        a1 = a1 * scale + vb;
        m = mx;
    }
    for (; i < cnt; ++i) {
        int r = csr[start + i];
        unsigned int qw = qkv[(size_t)r * 192 + l];
        unsigned int vw = qkv[(size_t)r * 192 + 128 + l];
        float p = fmaf(bflo(qw), kx, bfhi(qw) * ky);
        p += __shfl_xor(p, 1);
        p += __shfl_xor(p, 2);
        p += __shfl_xor(p, 4);
        float sc = p * 0.25f;
        float mn = fmaxf(m, sc);
        float scale = __expf(m - mn);
        float e = __expf(sc - mn);
        lsum = lsum * scale + e;
        a0 = a0 * scale + e * bflo(vw);
        a1 = a1 * scale + e * bfhi(vw);
        m = mn;
    }
    float inv = 1.f / (lsum + 1e-8f);
    unsigned int w = ((unsigned int)f2bf(a1 * inv) << 16) | (unsigned int)f2bf(a0 * inv);
    ob[(size_t)j * 64 + l] = w;
}

// -------------------------------- launch -----------------------------------

extern "C" void kernel_launch(void* const* d_in, const int* in_sizes, int n_in,
                              void* d_out, int out_size, void* d_ws, size_t ws_size,
                              hipStream_t stream) {
    const float* x   = (const float*)d_in[0];
    const int* ei    = (const int*)d_in[1];      // int64 materialized as int32
    const float* Wq  = (const float*)d_in[2];
    const float* Wk  = (const float*)d_in[3];
    const float* Wv  = (const float*)d_in[4];
    const float* Wo  = (const float*)d_in[5];
    const float* bo  = (const float*)d_in[6];
    const float* Wf1 = (const float*)d_in[7];
    const float* bf1 = (const float*)d_in[8];
    const float* Wf2 = (const float*)d_in[9];
    const float* bf2 = (const float*)d_in[10];
    const float* g1  = (const float*)d_in[11];
    const float* b1  = (const float*)d_in[12];
    const float* g2  = (const float*)d_in[13];
    const float* b2  = (const float*)d_in[14];

    int N = in_sizes[0] / 128;
    int E = in_sizes[1] / 2;
    int N2 = ((N + 63) / 64) * 64;
    int NE = E + N;

    char* p = (char*)d_ws;
    auto alloc = [&](size_t bytes) -> char* {
        char* r = p;
        p += (bytes + 255) & ~(size_t)255;
        return r;
    };
    unsigned short* qkv = (unsigned short*)alloc((size_t)N2 * 384 * 2);
    unsigned short* ob  = (unsigned short*)alloc((size_t)N2 * 128 * 2);
    unsigned short* xb  = (unsigned short*)alloc((size_t)N2 * 128 * 2);
    unsigned short* x1b = (unsigned short*)alloc((size_t)N2 * 128 * 2);
    unsigned short* Wqkvt = (unsigned short*)alloc(3 * 128 * 128 * 2);
    unsigned short* Wot   = (unsigned short*)alloc(128 * 128 * 2);
    unsigned short* Wf1t  = (unsigned short*)alloc(512 * 128 * 2);
    unsigned short* Wf2t  = (unsigned short*)alloc(128 * 512 * 2);
    int* counts = (int*)alloc((size_t)N * 4);
    int* incl   = (int*)alloc((size_t)N * 4);
    int* nstart = (int*)alloc((size_t)N * 4);
    int* cursor = (int*)alloc((size_t)N * 4);
    int* bsums  = (int*)alloc(1024 * 4);
    int* boffs  = (int*)alloc(1024 * 4);
    int* csr    = (int*)alloc((size_t)NE * 4);

    int NB = (N + 255) / 256;          // 196 (<256, one-block scan2)
    int M32 = (N + 31) / 32;           // 1563
    int M64 = (N + 63) / 64;           // 782

    k_zero<<<NB, 256, 0, stream>>>(counts, N);
    k_count<<<(NE + 255) / 256, 256, 0, stream>>>(ei, counts, E, N);
    k_scan1<<<NB, 256, 0, stream>>>(counts, incl, bsums, N);
    k_scan2<<<1, 256, 0, stream>>>(bsums, boffs, NB);
    k_scan3<<<NB, 256, 0, stream>>>(incl, counts, boffs, nstart, cursor, N);
    k_fill<<<(NE + 255) / 256, 256, 0, stream>>>(ei, cursor, csr, E, N);

    k_cast<<<((N * 128 / 4) + 255) / 256, 256, 0, stream>>>(x, xb, N * 128 / 4);
    k_prep<<<dim3(256, 6), 256, 0, stream>>>(Wq, Wk, Wv, Wo, Wf1, Wf2,
                                             Wqkvt, Wot, Wf1t, Wf2t);

    // QKV: xb [N][128] @ Wqkvt [384][128] -> qkv [N][384]
    k_stream<0, 3><<<dim3(M32, 2), 192, 0, stream>>>(xb, Wqkvt, nullptr, qkv, N, 384);

    k_attn<<<(N + 3) / 4, 256, 0, stream>>>((const unsigned int*)qkv, nstart,
                                            counts, csr, (unsigned int*)ob, N);

    // Wo + bias + residual(xb bf16) + LN1 -> x1b bf16
    k_woln<<<dim3(M32), 128, 0, stream>>>(ob, Wot, bo, xb, g1, b1, x1b, N);

    // fused FFN1 + gelu + FFN2 + bias + residual(x1b) + LN2 -> d_out fp32
    k_ffn<<<dim3(M64), 256, 0, stream>>>(x1b, Wf1t, bf1, Wf2t, bf2, g2, b2,
                                         (float*)d_out, N);
}

// Round 8
// 401.075 us; speedup vs baseline: 1.0673x; 1.0673x over previous
//
#include <hip/hip_runtime.h>
#include <cmath>

// ---------------------------------------------------------------------------
// GraphTransformerLayer on MI355X (gfx950).
// N=50000 nodes, C=128, H=8 heads, D=16, E=800000 edges (+N self loops).
//
// Pipeline (13 dispatches):
//   zero -> CSR build (count/scan x3/fill)      [edge_index arrives as INT32]
//   k_cast x->bf16 ; k_prep weights -> bf16 [Cout][K]
//   k_gs<0>: QKV, B-in-regs, grid-stride        -> qkv bf16 [N][384]
//   k_attn : 1 wave/dest node, 8-edge batches   -> ob bf16
//   k_woln : K=128 GEMM + bias+resid+LN1        -> x1b bf16
//   k_gs<1>: FFN1 + gelu                        -> hb bf16 [N][512]
//   k_ffn2ln: K=512 GEMM + bias+resid+LN2       -> d_out fp32
//
// r4-r7 lesson: these GEMMs were never BW- or MFMA-bound — they were VALU/
// latency-bound on the epilogue (32 scalar 2B stores/lane + addr math) and
// on B-refetch. Fix: TRANSPOSED mfma (operands swapped: lane=C-row,
// quad*4+reg = 4 consecutive C-cols) -> pack 8B -> wave-private LDS tile
// (rotated-col swizzle) -> 4 fully-coalesced 1KB stores per 32x64 strip.
// B-slice stays in 64 VGPRs (K=128) with grid-stride strip loop.
// ---------------------------------------------------------------------------

typedef short bf16x8 __attribute__((ext_vector_type(8)));
typedef float f32x4 __attribute__((ext_vector_type(4)));

__device__ inline unsigned short f2bf(float f) {
    unsigned int u = __float_as_uint(f);
    u += 0x7fffu + ((u >> 16) & 1u);   // round-to-nearest-even
    return (unsigned short)(u >> 16);
}
__device__ inline float bflo(unsigned int w) { return __uint_as_float(w << 16); }
__device__ inline float bfhi(unsigned int w) { return __uint_as_float(w & 0xffff0000u); }
__device__ inline float b2f(unsigned short u) { return __uint_as_float((unsigned int)u << 16); }

// ------------------------------- CSR build ---------------------------------

__global__ void k_zero(int* __restrict__ p, int n) {
    int i = blockIdx.x * 256 + threadIdx.x;
    if (i < n) p[i] = 0;
}

__global__ void k_count(const int* __restrict__ ei, int* __restrict__ counts,
                        int E, int N) {
    int e = blockIdx.x * 256 + threadIdx.x;
    if (e >= E + N) return;
    int col = (e < E) ? ei[E + e] : (e - E);
    atomicAdd(&counts[col], 1);
}

__global__ void k_scan1(const int* __restrict__ counts, int* __restrict__ incl,
                        int* __restrict__ bsums, int N) {
    __shared__ int s[256];
    int t = threadIdx.x, i = blockIdx.x * 256 + t;
    int v = (i < N) ? counts[i] : 0;
    s[t] = v; __syncthreads();
    for (int off = 1; off < 256; off <<= 1) {
        int add = (t >= off) ? s[t - off] : 0;
        __syncthreads();
        s[t] += add;
        __syncthreads();
    }
    if (i < N) incl[i] = s[t];
    if (t == 255) bsums[blockIdx.x] = s[255];
}

__global__ void k_scan2(const int* __restrict__ bsums, int* __restrict__ boffs, int NB) {
    __shared__ int s[256];
    int t = threadIdx.x;
    int v = (t < NB) ? bsums[t] : 0;
    s[t] = v; __syncthreads();
    for (int off = 1; off < 256; off <<= 1) {
        int add = (t >= off) ? s[t - off] : 0;
        __syncthreads();
        s[t] += add;
        __syncthreads();
    }
    if (t < NB) boffs[t] = s[t] - v;   // exclusive
}

__global__ void k_scan3(const int* __restrict__ incl, const int* __restrict__ counts,
                        const int* __restrict__ boffs, int* __restrict__ nstart,
                        int* __restrict__ cursor, int N) {
    int i = blockIdx.x * 256 + threadIdx.x;
    if (i >= N) return;
    int st = incl[i] - counts[i] + boffs[blockIdx.x];
    nstart[i] = st;
    cursor[i] = st;
}

__global__ void k_fill(const int* __restrict__ ei, int* __restrict__ cursor,
                       int* __restrict__ csr, int E, int N) {
    int e = blockIdx.x * 256 + threadIdx.x;
    if (e >= E + N) return;
    int row, col;
    if (e < E) { row = ei[e]; col = ei[E + e]; }
    else       { row = col = e - E; }
    int pos = atomicAdd(&cursor[col], 1);
    csr[pos] = row;
}

// ------------------------------ prep (casts) -------------------------------

__global__ void k_cast(const float* __restrict__ x, unsigned short* __restrict__ xb,
                       int total4) {
    int i = blockIdx.x * 256 + threadIdx.x;
    if (i >= total4) return;
    float4 v = ((const float4*)x)[i];
    ushort4 o;
    o.x = f2bf(v.x); o.y = f2bf(v.y); o.z = f2bf(v.z); o.w = f2bf(v.w);
    ((ushort4*)xb)[i] = o;
}

// transpose fp32 [K][Co] -> bf16 [Co][K].  Wq/Wk/Wv land contiguously.
__global__ void k_prep(const float* Wq, const float* Wk, const float* Wv, const float* Wo,
                       const float* Wf1, const float* Wf2,
                       unsigned short* Wqkvt, unsigned short* Wot,
                       unsigned short* Wf1t, unsigned short* Wf2t) {
    int z = blockIdx.y;
    const float* in; unsigned short* out; int K, Co;
    switch (z) {
        case 0: in = Wq;  out = Wqkvt;          K = 128; Co = 128; break;
        case 1: in = Wk;  out = Wqkvt + 16384;  K = 128; Co = 128; break;
        case 2: in = Wv;  out = Wqkvt + 32768;  K = 128; Co = 128; break;
        case 3: in = Wo;  out = Wot;            K = 128; Co = 128; break;
        case 4: in = Wf1; out = Wf1t;           K = 128; Co = 512; break;
        default: in = Wf2; out = Wf2t;          K = 512; Co = 128; break;
    }
    int idx = blockIdx.x * 256 + threadIdx.x;
    if (idx >= K * Co) return;
    int k = idx / Co, c = idx % Co;
    out[c * K + k] = f2bf(in[idx]);
}

// --------------------- transposed-store helpers ----------------------------
// acc[ti][bj] from mfma(bfrag, afrag): lane l16 = C-row (m0+ti*16+l16),
// quad*4+reg = C-col (n0+bj*16+quad*4+r). Pack 4 cols -> 8B, bounce through
// a wave-private 32x64 LDS tile (col rotated by (row&7)*8), read back
// row-major 16B chunks -> 4 coalesced 1KB stores.

__device__ inline void store_tile_bf16(unsigned short* lds, f32x4 acc[2][4],
                                       int lane, int m0, int n0, int M, int Cout,
                                       unsigned short* __restrict__ out) {
    int quad = lane >> 4, l16 = lane & 15;
    int rot = (l16 & 7) * 8;
#pragma unroll
    for (int ti = 0; ti < 2; ++ti) {
        int rowl = ti * 16 + l16;
#pragma unroll
        for (int bj = 0; bj < 4; ++bj) {
            int colr = (bj * 16 + quad * 4 + rot) & 63;
            uint2 pk;
            pk.x = ((unsigned int)f2bf(acc[ti][bj][1]) << 16) | f2bf(acc[ti][bj][0]);
            pk.y = ((unsigned int)f2bf(acc[ti][bj][3]) << 16) | f2bf(acc[ti][bj][2]);
            *(uint2*)(lds + rowl * 64 + colr) = pk;
        }
    }
#pragma unroll
    for (int t = 0; t < 4; ++t) {
        int ci = t * 64 + lane;
        int rowl = ci >> 3, cc = ci & 7;
        int scc = (cc + (rowl & 7)) & 7;
        bf16x8 v = *(const bf16x8*)(lds + rowl * 64 + scc * 8);
        int row = m0 + rowl;
        if (row < M)
            *(bf16x8*)(out + (size_t)row * Cout + n0 + cc * 8) = v;
    }
}

// ---------------- K=128 streaming GEMM (QKV / FFN1) ------------------------
// 1 wave per block; B-slice (64 cols x 128) stationary in 64 VGPRs;
// grid-stride over 32-row strips. EPI 0: plain. EPI 1: +bias, gelu.

template <int EPI>
__global__ __launch_bounds__(64) void k_gs(
    const unsigned short* __restrict__ A, const unsigned short* __restrict__ Bt,
    const float* __restrict__ bias, unsigned short* __restrict__ outb,
    int M, int S, int Cout) {
    __shared__ unsigned short lds[2048];
    int lane = threadIdx.x;
    int quad = lane >> 4, l16 = lane & 15;
    int n0 = blockIdx.y * 64;

    bf16x8 Breg[4][4];                         // [ks][bj]
#pragma unroll
    for (int bj = 0; bj < 4; ++bj) {
        const bf16x8* Br = (const bf16x8*)(Bt + (size_t)(n0 + bj * 16 + l16) * 128);
#pragma unroll
        for (int ks = 0; ks < 4; ++ks) Breg[ks][bj] = Br[ks * 4 + quad];
    }
    float4 bv[4];
    if (EPI == 1) {
#pragma unroll
        for (int bj = 0; bj < 4; ++bj)
            bv[bj] = *(const float4*)&bias[n0 + bj * 16 + quad * 4];
    }

    for (int s = blockIdx.x; s < S; s += gridDim.x) {
        int m0 = s * 32;
        f32x4 acc[2][4];
#pragma unroll
        for (int i = 0; i < 2; ++i)
#pragma unroll
            for (int j = 0; j < 4; ++j) acc[i][j] = {0.f, 0.f, 0.f, 0.f};
        int ra0 = min(m0 + l16, M - 1), ra1 = min(m0 + 16 + l16, M - 1);
        const bf16x8* A0 = (const bf16x8*)(A + (size_t)ra0 * 128);
        const bf16x8* A1 = (const bf16x8*)(A + (size_t)ra1 * 128);
#pragma unroll
        for (int ks = 0; ks < 4; ++ks) {
            bf16x8 a0 = A0[ks * 4 + quad];
            bf16x8 a1 = A1[ks * 4 + quad];
#pragma unroll
            for (int bj = 0; bj < 4; ++bj) {
                acc[0][bj] = __builtin_amdgcn_mfma_f32_16x16x32_bf16(Breg[ks][bj], a0, acc[0][bj], 0, 0, 0);
                acc[1][bj] = __builtin_amdgcn_mfma_f32_16x16x32_bf16(Breg[ks][bj], a1, acc[1][bj], 0, 0, 0);
            }
        }
        if constexpr (EPI == 1) {
#pragma unroll
            for (int ti = 0; ti < 2; ++ti)
#pragma unroll
                for (int bj = 0; bj < 4; ++bj)
#pragma unroll
                    for (int r = 0; r < 4; ++r) {
                        float gg = acc[ti][bj][r] + ((const float*)&bv[bj])[r];
                        acc[ti][bj][r] = 0.5f * gg * (1.f + erff(gg * 0.70710678118f));
                    }
        }
        store_tile_bf16(lds, acc, lane, m0, n0, M, Cout, outb);
    }
}

// ---------------- Wo GEMM (K=128) + bias + resid + LN1 ---------------------
// 2 waves/block (col-halves); B stationary per wave; grid-stride strips;
// one barrier/strip (double-buffered partial arrays).

__global__ __launch_bounds__(128) void k_woln(
    const unsigned short* __restrict__ A, const unsigned short* __restrict__ Bt,
    const float* __restrict__ bias, const unsigned short* __restrict__ residb,
    const float* __restrict__ g, const float* __restrict__ b,
    unsigned short* __restrict__ outb, int M, int S) {
    __shared__ unsigned short tl[2][2048];
    __shared__ float pS[2][2][32], pQ[2][2][32];
    int tid = threadIdx.x, wid = tid >> 6, lane = tid & 63;
    int quad = lane >> 4, l16 = lane & 15;
    int n0 = wid * 64;

    bf16x8 Breg[4][4];
#pragma unroll
    for (int bj = 0; bj < 4; ++bj) {
        const bf16x8* Br = (const bf16x8*)(Bt + (size_t)(n0 + bj * 16 + l16) * 128);
#pragma unroll
        for (int ks = 0; ks < 4; ++ks) Breg[ks][bj] = Br[ks * 4 + quad];
    }
    float4 bv[4], gv[4], bb[4];
#pragma unroll
    for (int bj = 0; bj < 4; ++bj) {
        int c4 = n0 + bj * 16 + quad * 4;
        bv[bj] = *(const float4*)&bias[c4];
        gv[bj] = *(const float4*)&g[c4];
        bb[bj] = *(const float4*)&b[c4];
    }

    int par = 0;
    for (int s = blockIdx.x; s < S; s += gridDim.x, par ^= 1) {
        int m0 = s * 32;
        f32x4 acc[2][4];
#pragma unroll
        for (int i = 0; i < 2; ++i)
#pragma unroll
            for (int j = 0; j < 4; ++j) acc[i][j] = {0.f, 0.f, 0.f, 0.f};
        int ra0 = min(m0 + l16, M - 1), ra1 = min(m0 + 16 + l16, M - 1);
        const bf16x8* A0 = (const bf16x8*)(A + (size_t)ra0 * 128);
        const bf16x8* A1 = (const bf16x8*)(A + (size_t)ra1 * 128);
#pragma unroll
        for (int ks = 0; ks < 4; ++ks) {
            bf16x8 a0 = A0[ks * 4 + quad];
            bf16x8 a1 = A1[ks * 4 + quad];
#pragma unroll
            for (int bj = 0; bj < 4; ++bj) {
                acc[0][bj] = __builtin_amdgcn_mfma_f32_16x16x32_bf16(Breg[ks][bj], a0, acc[0][bj], 0, 0, 0);
                acc[1][bj] = __builtin_amdgcn_mfma_f32_16x16x32_bf16(Breg[ks][bj], a1, acc[1][bj], 0, 0, 0);
            }
        }
        // + bias + residual (8B bf16 gathers, row = m0+ti*16+l16)
#pragma unroll
        for (int ti = 0; ti < 2; ++ti) {
            int rr = min(m0 + ti * 16 + l16, M - 1);
#pragma unroll
            for (int bj = 0; bj < 4; ++bj) {
                ushort4 rv = *(const ushort4*)&residb[(size_t)rr * 128 + n0 + bj * 16 + quad * 4];
                acc[ti][bj][0] += ((const float*)&bv[bj])[0] + b2f(rv.x);
                acc[ti][bj][1] += ((const float*)&bv[bj])[1] + b2f(rv.y);
                acc[ti][bj][2] += ((const float*)&bv[bj])[2] + b2f(rv.z);
                acc[ti][bj][3] += ((const float*)&bv[bj])[3] + b2f(rv.w);
            }
        }
        // per-row partials over this wave's 64 cols (reduce across quads)
#pragma unroll
        for (int ti = 0; ti < 2; ++ti) {
            float sm = 0.f, qq = 0.f;
#pragma unroll
            for (int bj = 0; bj < 4; ++bj)
#pragma unroll
                for (int r = 0; r < 4; ++r) {
                    float v = acc[ti][bj][r];
                    sm += v; qq += v * v;
                }
            sm += __shfl_xor(sm, 16); qq += __shfl_xor(qq, 16);
            sm += __shfl_xor(sm, 32); qq += __shfl_xor(qq, 32);
            if (quad == 0) {
                pS[par][wid][ti * 16 + l16] = sm;
                pQ[par][wid][ti * 16 + l16] = qq;
            }
        }
        __syncthreads();
#pragma unroll
        for (int ti = 0; ti < 2; ++ti) {
            int rowl = ti * 16 + l16;
            float sm = pS[par][0][rowl] + pS[par][1][rowl];
            float qq = pQ[par][0][rowl] + pQ[par][1][rowl];
            float mean = sm * 0.0078125f;
            float var = qq * 0.0078125f - mean * mean;
            float rs = rsqrtf(var + 1e-5f);
#pragma unroll
            for (int bj = 0; bj < 4; ++bj)
#pragma unroll
                for (int r = 0; r < 4; ++r)
                    acc[ti][bj][r] = (acc[ti][bj][r] - mean) * rs *
                        ((const float*)&gv[bj])[r] + ((const float*)&bb[bj])[r];
        }
        store_tile_bf16(tl[wid], acc, lane, m0, n0, M, 128, outb);
    }
}

// ---------------- FFN2 (K=512) + bias + resid + LN2 ------------------------
// 2 waves/block; B streamed (same addrs every strip -> L1/L2-hot);
// out fp32 direct 16B stores (4 consecutive cols per lane).

__global__ __launch_bounds__(128) void k_ffn2ln(
    const unsigned short* __restrict__ A, const unsigned short* __restrict__ Bt,
    const float* __restrict__ bias, const unsigned short* __restrict__ residb,
    const float* __restrict__ g, const float* __restrict__ b,
    float* __restrict__ outp, int M, int S) {
    __shared__ float pS[2][2][32], pQ[2][2][32];
    int tid = threadIdx.x, wid = tid >> 6, lane = tid & 63;
    int quad = lane >> 4, l16 = lane & 15;
    int n0 = wid * 64;

    const bf16x8* Brow[4];
#pragma unroll
    for (int bj = 0; bj < 4; ++bj)
        Brow[bj] = (const bf16x8*)(Bt + (size_t)(n0 + bj * 16 + l16) * 512);
    float4 bv[4], gv[4], bb[4];
#pragma unroll
    for (int bj = 0; bj < 4; ++bj) {
        int c4 = n0 + bj * 16 + quad * 4;
        bv[bj] = *(const float4*)&bias[c4];
        gv[bj] = *(const float4*)&g[c4];
        bb[bj] = *(const float4*)&b[c4];
    }

    int par = 0;
    for (int s = blockIdx.x; s < S; s += gridDim.x, par ^= 1) {
        int m0 = s * 32;
        f32x4 acc[2][4];
#pragma unroll
        for (int i = 0; i < 2; ++i)
#pragma unroll
            for (int j = 0; j < 4; ++j) acc[i][j] = {0.f, 0.f, 0.f, 0.f};
        int ra0 = min(m0 + l16, M - 1), ra1 = min(m0 + 16 + l16, M - 1);
        const bf16x8* A0 = (const bf16x8*)(A + (size_t)ra0 * 512);
        const bf16x8* A1 = (const bf16x8*)(A + (size_t)ra1 * 512);
#pragma unroll 4
        for (int ks = 0; ks < 16; ++ks) {
            bf16x8 a0 = A0[ks * 4 + quad];
            bf16x8 a1 = A1[ks * 4 + quad];
#pragma unroll
            for (int bj = 0; bj < 4; ++bj) {
                bf16x8 bf = Brow[bj][ks * 4 + quad];
                acc[0][bj] = __builtin_amdgcn_mfma_f32_16x16x32_bf16(bf, a0, acc[0][bj], 0, 0, 0);
                acc[1][bj] = __builtin_amdgcn_mfma_f32_16x16x32_bf16(bf, a1, acc[1][bj], 0, 0, 0);
            }
        }
#pragma unroll
        for (int ti = 0; ti < 2; ++ti) {
            int rr = min(m0 + ti * 16 + l16, M - 1);
#pragma unroll
            for (int bj = 0; bj < 4; ++bj) {
                ushort4 rv = *(const ushort4*)&residb[(size_t)rr * 128 + n0 + bj * 16 + quad * 4];
                acc[ti][bj][0] += ((const float*)&bv[bj])[0] + b2f(rv.x);
                acc[ti][bj][1] += ((const float*)&bv[bj])[1] + b2f(rv.y);
                acc[ti][bj][2] += ((const float*)&bv[bj])[2] + b2f(rv.z);
                acc[ti][bj][3] += ((const float*)&bv[bj])[3] + b2f(rv.w);
            }
        }
#pragma unroll
        for (int ti = 0; ti < 2; ++ti) {
            float sm = 0.f, qq = 0.f;
#pragma unroll
            for (int bj = 0; bj < 4; ++bj)
#pragma unroll
                for (int r = 0; r < 4; ++r) {
                    float v = acc[ti][bj][r];
                    sm += v; qq += v * v;
                }
            sm += __shfl_xor(sm, 16); qq += __shfl_xor(qq, 16);
            sm += __shfl_xor(sm, 32); qq += __shfl_xor(qq, 32);
            if (quad == 0) {
                pS[par][wid][ti * 16 + l16] = sm;
                pQ[par][wid][ti * 16 + l16] = qq;
            }
        }
        __syncthreads();
#pragma unroll
        for (int ti = 0; ti < 2; ++ti) {
            int rowl = ti * 16 + l16;
            int row = m0 + rowl;
            float sm = pS[par][0][rowl] + pS[par][1][rowl];
            float qq = pQ[par][0][rowl] + pQ[par][1][rowl];
            float mean = sm * 0.0078125f;
            float var = qq * 0.0078125f - mean * mean;
            float rs = rsqrtf(var + 1e-5f);
            if (row < M) {
#pragma unroll
                for (int bj = 0; bj < 4; ++bj) {
                    float4 o;
                    o.x = (acc[ti][bj][0] - mean) * rs * ((const float*)&gv[bj])[0] + ((const float*)&bb[bj])[0];
                    o.y = (acc[ti][bj][1] - mean) * rs * ((const float*)&gv[bj])[1] + ((const float*)&bb[bj])[1];
                    o.z = (acc[ti][bj][2] - mean) * rs * ((const float*)&gv[bj])[2] + ((const float*)&bb[bj])[2];
                    o.w = (acc[ti][bj][3] - mean) * rs * ((const float*)&gv[bj])[3] + ((const float*)&bb[bj])[3];
                    *(float4*)&outp[(size_t)row * 128 + n0 + bj * 16 + quad * 4] = o;
                }
            }
        }
    }
}

// ------------------------------ attention ----------------------------------
// One wave per destination node j; qkv row = [q|k|v] (192 dwords). Lane l
// owns channels (2l,2l+1); lanes 8h..8h+7 hold head h -> 3 shfl_xor reduce.
// 8-edge batches: 16 gathers in flight, one batched online-softmax update.

__global__ __launch_bounds__(256) void k_attn(
    const unsigned int* __restrict__ qkv, const int* __restrict__ nstart,
    const int* __restrict__ counts, const int* __restrict__ csr,
    unsigned int* __restrict__ ob, int N) {
    int j = blockIdx.x * 4 + (threadIdx.x >> 6);
    if (j >= N) return;
    int l = threadIdx.x & 63;

    unsigned int kw = qkv[(size_t)j * 192 + 64 + l];
    float kx = bflo(kw), ky = bfhi(kw);

    int start = nstart[j], cnt = counts[j];
    float m = -3.0e38f, lsum = 0.f, a0 = 0.f, a1 = 0.f;
    int i = 0;
    for (; i + 8 <= cnt; i += 8) {
        int ri[8];
#pragma unroll
        for (int u = 0; u < 8; ++u) ri[u] = csr[start + i + u];
        unsigned int qw[8], vw[8];
#pragma unroll
        for (int u = 0; u < 8; ++u) qw[u] = qkv[(size_t)ri[u] * 192 + l];
#pragma unroll
        for (int u = 0; u < 8; ++u) vw[u] = qkv[(size_t)ri[u] * 192 + 128 + l];

        float p[8];
#pragma unroll
        for (int u = 0; u < 8; ++u) p[u] = fmaf(bflo(qw[u]), kx, bfhi(qw[u]) * ky);
#pragma unroll
        for (int u = 0; u < 8; ++u) p[u] += __shfl_xor(p[u], 1);
#pragma unroll
        for (int u = 0; u < 8; ++u) p[u] += __shfl_xor(p[u], 2);
#pragma unroll
        for (int u = 0; u < 8; ++u) p[u] += __shfl_xor(p[u], 4);

        float mx = m;
#pragma unroll
        for (int u = 0; u < 8; ++u) { p[u] *= 0.25f; mx = fmaxf(mx, p[u]); }
        float scale = __expf(m - mx);
        float e[8], es = 0.f, va = 0.f, vb = 0.f;
#pragma unroll
        for (int u = 0; u < 8; ++u) {
            e[u] = __expf(p[u] - mx);
            es += e[u];
            va = fmaf(e[u], bflo(vw[u]), va);
            vb = fmaf(e[u], bfhi(vw[u]), vb);
        }
        lsum = lsum * scale + es;
        a0 = a0 * scale + va;
        a1 = a1 * scale + vb;
        m = mx;
    }
    for (; i < cnt; ++i) {
        int r = csr[start + i];
        unsigned int qw = qkv[(size_t)r * 192 + l];
        unsigned int vw = qkv[(size_t)r * 192 + 128 + l];
        float p = fmaf(bflo(qw), kx, bfhi(qw) * ky);
        p += __shfl_xor(p, 1);
        p += __shfl_xor(p, 2);
        p += __shfl_xor(p, 4);
        float sc = p * 0.25f;
        float mn = fmaxf(m, sc);
        float scale = __expf(m - mn);
        float e = __expf(sc - mn);
        lsum = lsum * scale + e;
        a0 = a0 * scale + e * bflo(vw);
        a1 = a1 * scale + e * bfhi(vw);
        m = mn;
    }
    float inv = 1.f / (lsum + 1e-8f);
    unsigned int w = ((unsigned int)f2bf(a1 * inv) << 16) | (unsigned int)f2bf(a0 * inv);
    ob[(size_t)j * 64 + l] = w;
}

// -------------------------------- launch -----------------------------------

extern "C" void kernel_launch(void* const* d_in, const int* in_sizes, int n_in,
                              void* d_out, int out_size, void* d_ws, size_t ws_size,
                              hipStream_t stream) {
    const float* x   = (const float*)d_in[0];
    const int* ei    = (const int*)d_in[1];      // int64 materialized as int32
    const float* Wq  = (const float*)d_in[2];
    const float* Wk  = (const float*)d_in[3];
    const float* Wv  = (const float*)d_in[4];
    const float* Wo  = (const float*)d_in[5];
    const float* bo  = (const float*)d_in[6];
    const float* Wf1 = (const float*)d_in[7];
    const float* bf1 = (const float*)d_in[8];
    const float* Wf2 = (const float*)d_in[9];
    const float* bf2 = (const float*)d_in[10];
    const float* g1  = (const float*)d_in[11];
    const float* b1  = (const float*)d_in[12];
    const float* g2  = (const float*)d_in[13];
    const float* b2  = (const float*)d_in[14];

    int N = in_sizes[0] / 128;
    int E = in_sizes[1] / 2;
    int N2 = ((N + 31) / 32) * 32;
    int NE = E + N;
    int S = (N + 31) / 32;             // 1563 row strips

    char* p = (char*)d_ws;
    auto alloc = [&](size_t bytes) -> char* {
        char* r = p;
        p += (bytes + 255) & ~(size_t)255;
        return r;
    };
    // R0: [qkv (N2*384) | ob (N2*128)] bf16, reused as hb [N2][512] for FFN.
    unsigned short* qkv = (unsigned short*)alloc((size_t)N2 * 512 * 2);
    unsigned short* ob  = qkv + (size_t)N2 * 384;
    unsigned short* hb  = qkv;                   // alias (lifetime disjoint)
    unsigned short* xb  = (unsigned short*)alloc((size_t)N2 * 128 * 2);
    unsigned short* x1b = (unsigned short*)alloc((size_t)N2 * 128 * 2);
    unsigned short* Wqkvt = (unsigned short*)alloc(3 * 128 * 128 * 2);
    unsigned short* Wot   = (unsigned short*)alloc(128 * 128 * 2);
    unsigned short* Wf1t  = (unsigned short*)alloc(512 * 128 * 2);
    unsigned short* Wf2t  = (unsigned short*)alloc(128 * 512 * 2);
    int* counts = (int*)alloc((size_t)N * 4);
    int* incl   = (int*)alloc((size_t)N * 4);
    int* nstart = (int*)alloc((size_t)N * 4);
    int* cursor = (int*)alloc((size_t)N * 4);
    int* bsums  = (int*)alloc(1024 * 4);
    int* boffs  = (int*)alloc(1024 * 4);
    int* csr    = (int*)alloc((size_t)NE * 4);

    int NB = (N + 255) / 256;          // 196 (<256, one-block scan2)

    k_zero<<<NB, 256, 0, stream>>>(counts, N);
    k_count<<<(NE + 255) / 256, 256, 0, stream>>>(ei, counts, E, N);
    k_scan1<<<NB, 256, 0, stream>>>(counts, incl, bsums, N);
    k_scan2<<<1, 256, 0, stream>>>(bsums, boffs, NB);
    k_scan3<<<NB, 256, 0, stream>>>(incl, counts, boffs, nstart, cursor, N);
    k_fill<<<(NE + 255) / 256, 256, 0, stream>>>(ei, cursor, csr, E, N);

    k_cast<<<((N * 128 / 4) + 255) / 256, 256, 0, stream>>>(x, xb, N * 128 / 4);
    k_prep<<<dim3(256, 6), 256, 0, stream>>>(Wq, Wk, Wv, Wo, Wf1, Wf2,
                                             Wqkvt, Wot, Wf1t, Wf2t);

    // QKV: xb [N][128] @ Wqkvt [384][128] -> qkv [N][384]
    k_gs<0><<<dim3(512, 6), 64, 0, stream>>>(xb, Wqkvt, nullptr, qkv, N, S, 384);

    k_attn<<<(N + 3) / 4, 256, 0, stream>>>((const unsigned int*)qkv, nstart,
                                            counts, csr, (unsigned int*)ob, N);

    // Wo + bias + residual(xb) + LN1 -> x1b bf16
    k_woln<<<dim3(1536), 128, 0, stream>>>(ob, Wot, bo, xb, g1, b1, x1b, N, S);

    // FFN1 + gelu -> hb (aliases qkv|ob, both dead)
    k_gs<1><<<dim3(384, 8), 64, 0, stream>>>(x1b, Wf1t, bf1, hb, N, S, 512);

    // FFN2 (K=512) + bias + residual(x1b) + LN2 -> d_out fp32
    k_ffn2ln<<<dim3(1536), 128, 0, stream>>>(hb, Wf2t, bf2, x1b, g2, b2,
                                             (float*)d_out, N, S);
}